// Round 11
// baseline (248.708 us; speedup 1.0000x reference)
//
#include <hip/hip_runtime.h>
#include <hip/hip_bf16.h>

// Fused per-type MLP chain (Linear -> ResBlock(silu,LN,Linear) -> silu-Linear -> dot)
// R16 (from R15/R12 @ 195us total / fused ~94us):
//  Only lever that ever moved fused was occupancy (R7: 8->16 waves/CU, -10us).
//  This round: MT=32 fine-grained convoys. 8 waves x (32 neurons x 32 atoms),
//  acc[2][2]=16 AGPR, LDS 46080B -> 3 blocks/CU = 24 waves/CU (needs regs<=85:
//  launch_bounds(512,6); est ~66 unified, R13 measured 84 with bigger acc).
//  Convoy phases halve (32 MFMA/wave/GEMM, 16 epi values/thread); tiles double
//  (2052); 3 independent convoys/CU hide each other's barrier stalls.
//  Cost: A-traffic x2 (L2-absorbed; R11 proved W traffic not time-critical).
//  Phase/barrier structure byte-identical to R12, re-indexed for 32 rows.
// MFMA 16x16x32 bf16 layouts (HW-verified per guide m89/m91):
//   A[m][k]: m = lane&15, k = (lane>>4)*8 + j   (W row-major: contiguous 16B)
//   B[k][n]: n = lane&15, k = (lane>>4)*8 + j   (Xs row  : contiguous 16B)
//   C/D:     n(atom) = lane&15, m(neuron) = (lane>>4)*4 + reg

#define D 256
#define T 4
#define MT 32            // atoms per block (halved vs R12)
#define NTHREADS 512     // 8 waves
#define CSTRIDE 32       // cursor padding: one counter per 128B cache line

// swizzled halfword index for element (row=atom, col=feature halfword)
#define XSW(row, col) (((row) << 8) + ((col) ^ (((row) & 7) << 3)))

typedef __attribute__((ext_vector_type(8))) short bf16x8;
typedef __attribute__((ext_vector_type(4))) float f32x4;

__device__ __forceinline__ float bf2f(unsigned short s) {
    union { unsigned u; float f; } c;
    c.u = ((unsigned)s) << 16;
    return c.f;
}
// packed f32x2 -> bf16x2, RNE (MODE default), 1 instr (guide T12 recipe, m240)
__device__ __forceinline__ unsigned cvtpk(float a, float b) {
    unsigned r;
    asm("v_cvt_pk_bf16_f32 %0, %1, %2" : "=v"(r) : "v"(a), "v"(b));
    return r;
}
__device__ __forceinline__ float lo2f(unsigned u) { return bf2f((unsigned short)(u & 0xffffu)); }
__device__ __forceinline__ float hi2f(unsigned u) { return bf2f((unsigned short)(u >> 16)); }
__device__ __forceinline__ float silu(float v) {
    return v * __builtin_amdgcn_rcpf(1.f + __expf(-v));
}

// LDS-only barrier (T4): waits own LDS ops, does NOT drain vmcnt.
__device__ __forceinline__ void barrier_lds() {
    __builtin_amdgcn_sched_barrier(0);
    asm volatile("s_waitcnt lgkmcnt(0)" ::: "memory");
    __builtin_amdgcn_s_barrier();
    __builtin_amdgcn_sched_barrier(0);
}

// ---------------- prep kernel (hist+scatter+convert merged) ----------------
// perm layout: capacity regions, type t's atoms at perm[t*N .. t*N+count[t])
extern "C" __global__ void k_prep(const int* __restrict__ species, int* cursors,
                                  int* __restrict__ perm, int N,
                                  const float* __restrict__ s0, const float* __restrict__ s1,
                                  const float* __restrict__ s2, const float* __restrict__ s3,
                                  unsigned short* __restrict__ d0, unsigned short* __restrict__ d1,
                                  unsigned short* __restrict__ d2, unsigned short* __restrict__ d3, int n4) {
    __shared__ int lh[T], lbase[T];
    int tid = threadIdx.x;
    if (tid < T) lh[tid] = 0;
    __syncthreads();
    int i = blockIdx.x * blockDim.x + tid;
    int t = -1, rank = 0;
    if (i < N) {
        t = species[i];
        rank = atomicAdd(&lh[t], 1);          // LDS atomic: block-local rank
    }
    if (i < n4) {   // weight fp32 -> bf16 (vectorized, cvt_pk); independent path
        float4 v;
        v = ((const float4*)s0)[i]; ((uint2*)d0)[i] = make_uint2(cvtpk(v.x, v.y), cvtpk(v.z, v.w));
        v = ((const float4*)s1)[i]; ((uint2*)d1)[i] = make_uint2(cvtpk(v.x, v.y), cvtpk(v.z, v.w));
        v = ((const float4*)s2)[i]; ((uint2*)d2)[i] = make_uint2(cvtpk(v.x, v.y), cvtpk(v.z, v.w));
        v = ((const float4*)s3)[i]; ((uint2*)d3)[i] = make_uint2(cvtpk(v.x, v.y), cvtpk(v.z, v.w));
    }
    __syncthreads();
    if (tid < T) lbase[tid] = atomicAdd(&cursors[tid * CSTRIDE], lh[tid]);  // 4/block, padded lines
    __syncthreads();
    if (t >= 0) perm[t * N + lbase[t] + rank] = i;
}

// ---------------- fused main kernel ----------------

extern "C" __global__ void __launch_bounds__(NTHREADS, 6)
fused_moe(const float* __restrict__ density,
          const int* __restrict__ perm,
          const int* __restrict__ counts,     // == padded cursors after k_prep
          const unsigned short* __restrict__ W0b,
          const unsigned short* __restrict__ Wab,
          const unsigned short* __restrict__ Wlb,
          const unsigned short* __restrict__ Wfb,
          const float* __restrict__ b0g, const float* __restrict__ bag,
          const float* __restrict__ aag, const float* __restrict__ gg,
          const float* __restrict__ btg, const float* __restrict__ blg,
          const float* __restrict__ bfg, const float* __restrict__ afg,
          const float* __restrict__ Wog, const float* __restrict__ bog,
          float* __restrict__ out, int N)
{
    __shared__ unsigned short Xs[2][MT * D];            // 2 x 16384 B, ping-pong, XOR-swizzled
    __shared__ float Pb0[D], Pba[D], Paa[D], Pg[D], Pbt[D], Pbl[D], Pbf[D], Paf[D], Pwo[D]; // 9216 B
    __shared__ float red1[NTHREADS], red2[NTHREADS];    // 4096 B; partials then mu/rs
    // total LDS = 46080 B -> 3 blocks/CU = 24 waves/CU (regs capped <=85 by
    // launch_bounds(512,6))

    const int tid = threadIdx.x;

    // ---- XCD-clustered work swizzle (bijective, m204) ----
    const int nwg = gridDim.x;
    const int qq = nwg >> 3, rr = nwg & 7;
    const int xcd = blockIdx.x & 7, lid = blockIdx.x >> 3;
    const int vb = (xcd < rr ? xcd * (qq + 1) : rr * (qq + 1) + (xcd - rr) * qq) + lid;

    // ---- which (type, tile) am I? ----
    int c[T];
#pragma unroll
    for (int i = 0; i < T; ++i) c[i] = counts[i * CSTRIDE];
    int t = -1, tile = 0, rem = vb;
#pragma unroll
    for (int i = 0; i < T; ++i) {
        int ti = (c[i] + MT - 1) >> 5;
        if (t < 0) {
            if (rem < ti) { t = i; tile = rem; }
            else rem -= ti;
        }
    }
    if (t < 0) return;
    const int bstart = t * N + tile * MT;               // capacity-region base
    const int nrows = min(MT, c[t] - tile * MT);

    const int lane = tid & 63;
    const int w    = tid >> 6;            // wave id 0..7 -> neuron 32-slice
    const int ml   = lane & 15;
    const int qk   = (lane >> 4) * 8;     // A/B fragment k offset
    const int qr   = (lane >> 4) * 4;     // C/D fragment neuron offset

    const size_t wmat = (size_t)t * D * D;
    const unsigned short* W0t = W0b + wmat;
    const unsigned short* Wat = Wab + wmat;
    const unsigned short* Wlt = Wlb + wmat;
    const unsigned short* Wft = Wfb + wmat;

    // ---- stage ALL per-type vectors once (tid<256 active) ----
    if (tid < D) {
        int j = t * D + tid;
        Pb0[tid] = b0g[j]; Pba[tid] = bag[j]; Paa[tid] = aag[j];
        Pg[tid]  = gg[j];  Pbt[tid] = btg[j]; Pbl[tid] = blg[j];
        Pbf[tid] = bfg[j]; Paf[tid] = afg[j]; Pwo[tid] = Wog[j];
    }

    // ---- gather X0 (fp32 -> bf16) into Xs[0][atom][feature] (swizzled) ----
    // 512 threads = 32 rows x 16 thread-cols; each thread 4 float4s
    {
        int row = tid >> 4;
        int cbase = (tid & 15) * 4;
        if (row < nrows) {
            const float* src = density + (size_t)perm[bstart + row] * D;
#pragma unroll
            for (int j = 0; j < 4; ++j) {
                int col = cbase + j * 64;
                float4 v = *(const float4*)(src + col);
                *(uint2*)(&Xs[0][XSW(row, col)]) = make_uint2(cvtpk(v.x, v.y), cvtpk(v.z, v.w));
            }
        } else {
#pragma unroll
            for (int j = 0; j < 4; ++j)
                *(uint2*)(&Xs[0][XSW(row, cbase + j * 64)]) = make_uint2(0u, 0u);
        }
    }
    barrier_lds();                                      // B1

    f32x4 acc[2][2];                      // 16 AGPRs (halved vs R12)
    const f32x4 zero4 = {0.f, 0.f, 0.f, 0.f};

    // Plain GEMM (R9/R13: explicit A-pipeline neutral); 4 MFMAs per k-step.
    auto do_gemm = [&](const unsigned short* __restrict__ W, const unsigned short* __restrict__ Xb) {
#pragma unroll
        for (int mi = 0; mi < 2; ++mi)
#pragma unroll
            for (int ni = 0; ni < 2; ++ni) acc[mi][ni] = zero4;
#pragma unroll
        for (int k0 = 0; k0 < D; k0 += 32) {
            bf16x8 a[2], b[2];
#pragma unroll
            for (int mi = 0; mi < 2; ++mi)
                a[mi] = *(const bf16x8*)(W + (size_t)(w * 32 + mi * 16 + ml) * D + k0 + qk);
#pragma unroll
            for (int ni = 0; ni < 2; ++ni)
                b[ni] = *(const bf16x8*)(Xb + XSW(ni * 16 + ml, k0 + qk));
#pragma unroll
            for (int mi = 0; mi < 2; ++mi)
#pragma unroll
                for (int ni = 0; ni < 2; ++ni)
                    acc[mi][ni] = __builtin_amdgcn_mfma_f32_16x16x32_bf16(
                        a[mi], b[ni], acc[mi][ni], 0, 0, 0);
        }
    };

    // lane owns atom a0 = ni*16+ml (0..31), neurons r0..r0+3 (contiguous)

    // ======== Phase 1: x1 = X0 @ W0^T + b0   (read Xs0, write Xs1) ========
    do_gemm(W0t, Xs[0]);
#pragma unroll
    for (int mi = 0; mi < 2; ++mi) {
#pragma unroll
        for (int ni = 0; ni < 2; ++ni) {
            int r0 = w * 32 + mi * 16 + qr;
            int a0 = ni * 16 + ml;
            float4 bb = *(const float4*)(Pb0 + r0);
            unsigned p01 = cvtpk(acc[mi][ni][0] + bb.x, acc[mi][ni][1] + bb.y);
            unsigned p23 = cvtpk(acc[mi][ni][2] + bb.z, acc[mi][ni][3] + bb.w);
            *(uint2*)(&Xs[1][XSW(a0, r0)]) = make_uint2(p01, p23);
        }
    }
    barrier_lds();                                      // B2

    // ======== Phase 2: h = alpha_a * silu(x1 @ Wa^T + ba)  (Xs1 -> Xs0) ========
    do_gemm(Wat, Xs[1]);
#pragma unroll
    for (int mi = 0; mi < 2; ++mi) {
#pragma unroll
        for (int ni = 0; ni < 2; ++ni) {
            int r0 = w * 32 + mi * 16 + qr;
            int a0 = ni * 16 + ml;
            float4 bb = *(const float4*)(Pba + r0);
            float4 aa = *(const float4*)(Paa + r0);
            float v0 = aa.x * silu(acc[mi][ni][0] + bb.x);
            float v1 = aa.y * silu(acc[mi][ni][1] + bb.y);
            float v2 = aa.z * silu(acc[mi][ni][2] + bb.z);
            float v3 = aa.w * silu(acc[mi][ni][3] + bb.w);
            *(uint2*)(&Xs[0][XSW(a0, r0)]) = make_uint2(cvtpk(v0, v1), cvtpk(v2, v3));
        }
    }
    barrier_lds();                                      // B3

    // ======== LayerNorm per atom: Xs0 IN PLACE (x1 survives in Xs1) ========
    // 32 rows x 16 thread-cols; each thread covers 16 cols = 2 octets
    {
        int row = tid >> 4, sub = tid & 15;
        int col0 = sub * 16;
        bf16x8 hv[2];
        float sum = 0.f, ssq = 0.f;
#pragma unroll
        for (int j = 0; j < 2; ++j) {
            hv[j] = *(const bf16x8*)(&Xs[0][XSW(row, col0 + j * 8)]);
#pragma unroll
            for (int e = 0; e < 8; ++e) {
                float f = bf2f((unsigned short)hv[j][e]);
                sum += f;
                ssq = fmaf(f, f, ssq);
            }
        }
        red1[tid] = sum; red2[tid] = ssq;               // red1[row*16+sub]
        barrier_lds();                                  // B4
        if (tid < MT) {   // all in wave 0: loop loads retire before stores
            float s = 0.f, sq = 0.f;
#pragma unroll
            for (int k = 0; k < 16; ++k) { s += red1[tid * 16 + k]; sq += red2[tid * 16 + k]; }
            float mu = s * (1.f / D);
            float var = sq * (1.f / D) - mu * mu;
            red1[tid] = mu;
            red2[tid] = rsqrtf(var + 1e-5f);
        }
        barrier_lds();                                  // B5
        float mu = red1[row], rs = red2[row];
#pragma unroll
        for (int j = 0; j < 2; ++j) {
            float n[8];
#pragma unroll
            for (int e = 0; e < 8; ++e) {
                int col = col0 + j * 8 + e;
                float f = bf2f((unsigned short)hv[j][e]);
                n[e] = fmaf((f - mu) * rs, Pg[col], Pbt[col]);
            }
            uint2 o = make_uint2(cvtpk(n[0], n[1]), cvtpk(n[2], n[3]));
            uint2 o2 = make_uint2(cvtpk(n[4], n[5]), cvtpk(n[6], n[7]));
            *(uint2*)(&Xs[0][XSW(row, col0 + j * 8)]) = o;
            *(uint2*)(&Xs[0][XSW(row, col0 + j * 8 + 4)]) = o2;
        }
    }
    barrier_lds();                                      // B6

    // ======== Phase 3: x3 = x1 + h @ Wl^T + bl  (read Xs0; x1 from Xs1; write Xs1) ========
    do_gemm(Wlt, Xs[0]);
#pragma unroll
    for (int mi = 0; mi < 2; ++mi) {
#pragma unroll
        for (int ni = 0; ni < 2; ++ni) {
            int r0 = w * 32 + mi * 16 + qr;
            int a0 = ni * 16 + ml;
            float4 bb = *(const float4*)(Pbl + r0);
            uint2 old = *(const uint2*)(&Xs[1][XSW(a0, r0)]);  // x1 (same thread re-writes)
            float v0 = acc[mi][ni][0] + bb.x + lo2f(old.x);
            float v1 = acc[mi][ni][1] + bb.y + hi2f(old.x);
            float v2 = acc[mi][ni][2] + bb.z + lo2f(old.y);
            float v3 = acc[mi][ni][3] + bb.w + hi2f(old.y);
            *(uint2*)(&Xs[1][XSW(a0, r0)]) = make_uint2(cvtpk(v0, v1), cvtpk(v2, v3));
        }
    }
    barrier_lds();                                      // B7

    // ======== Phase 4: x4 = alpha_f * silu(x3 @ Wf^T + bf)  (Xs1 -> Xs0) ========
    do_gemm(Wft, Xs[1]);
#pragma unroll
    for (int mi = 0; mi < 2; ++mi) {
#pragma unroll
        for (int ni = 0; ni < 2; ++ni) {
            int r0 = w * 32 + mi * 16 + qr;
            int a0 = ni * 16 + ml;
            float4 bb = *(const float4*)(Pbf + r0);
            float4 aa = *(const float4*)(Paf + r0);
            float v0 = aa.x * silu(acc[mi][ni][0] + bb.x);
            float v1 = aa.y * silu(acc[mi][ni][1] + bb.y);
            float v2 = aa.z * silu(acc[mi][ni][2] + bb.z);
            float v3 = aa.w * silu(acc[mi][ni][3] + bb.w);
            *(uint2*)(&Xs[0][XSW(a0, r0)]) = make_uint2(cvtpk(v0, v1), cvtpk(v2, v3));
        }
    }
    barrier_lds();                                      // B8

    // ======== Output: y = x4 . Wo[t] + bo[t]  (read Xs0) ========
    {
        int row = tid >> 4, sub = tid & 15;
        int col0 = sub * 16;
        float part = 0.f;
#pragma unroll
        for (int j = 0; j < 2; ++j) {
            bf16x8 hv = *(const bf16x8*)(&Xs[0][XSW(row, col0 + j * 8)]);
#pragma unroll
            for (int e = 0; e < 8; ++e)
                part = fmaf(bf2f((unsigned short)hv[e]), Pwo[col0 + j * 8 + e], part);
        }
        red1[tid] = part;                               // red1[row*16+sub]
        barrier_lds();                                  // B9
        if (tid < nrows) {
            float val = bog[t];
#pragma unroll
            for (int k = 0; k < 16; ++k) val += red1[tid * 16 + k];
            out[perm[bstart + tid]] = val;
        }
    }
}

// ---------------- launcher ----------------

extern "C" void kernel_launch(void* const* d_in, const int* in_sizes, int n_in,
                              void* d_out, int out_size, void* d_ws, size_t ws_size,
                              hipStream_t stream) {
    const float* density = (const float*)d_in[0];
    const int*   species = (const int*)d_in[1];
    const float* W0      = (const float*)d_in[2];
    const float* b0      = (const float*)d_in[3];
    const float* Wa      = (const float*)d_in[4];
    const float* ba      = (const float*)d_in[5];
    const float* alpha_a = (const float*)d_in[6];
    const float* gamma   = (const float*)d_in[7];
    const float* beta_ln = (const float*)d_in[8];
    const float* Wl      = (const float*)d_in[9];
    const float* bl      = (const float*)d_in[10];
    const float* Wf      = (const float*)d_in[11];
    const float* bfv     = (const float*)d_in[12];
    const float* alpha_f = (const float*)d_in[13];
    const float* Wo      = (const float*)d_in[14];
    const float* bo      = (const float*)d_in[15];
    float* out = (float*)d_out;
    const int N = in_sizes[1];

    // ws layout: [cursors 4 x 128B = 512B, pad to 1KB] [perm T*N ints = 1MB]
    //            [bf16 weights 4 x 512KB]
    char* ws = (char*)d_ws;
    int* cursors = (int*)ws;
    int* perm    = (int*)(ws + 1024);
    const size_t wsz = (size_t)T * D * D;       // elems per weight tensor
    unsigned short* W0b = (unsigned short*)(ws + 1024 + (size_t)T * N * 4);
    unsigned short* Wab = W0b + wsz;
    unsigned short* Wlb = Wab + wsz;
    unsigned short* Wfb = Wlb + wsz;

    hipMemsetAsync(ws, 0, 512, stream);         // padded cursors
    int n4 = (int)(wsz / 4);
    int pb = ((N > n4 ? N : n4) + 255) / 256;
    k_prep<<<pb, 256, 0, stream>>>(species, cursors, perm, N, W0, Wa, Wl, Wf,
                                   W0b, Wab, Wlb, Wfb, n4);

    int nblocks = (N + MT - 1) / MT + T;
    fused_moe<<<nblocks, NTHREADS, 0, stream>>>(density, perm, cursors, W0b, Wab, Wlb, Wfb,
                                                b0, ba, alpha_a, gamma, beta_ln, bl, bfv, alpha_f,
                                                Wo, bo, out, N);
}

// Round 13
// 195.828 us; speedup vs baseline: 1.2700x; 1.2700x over previous
//
#include <hip/hip_runtime.h>
#include <hip/hip_bf16.h>

// Fused per-type MLP chain (Linear -> ResBlock(silu,LN,Linear) -> silu-Linear -> dot)
// R18 = resubmit of R17 (byte-identical to R15/R12, the session optimum:
// 194.4-195.0us total, fused ~93-95us — verified in Round 10). R17's bench
// never ran (GPUAcquisitionTimeout x2).
//  Session constraint box (all measured): finer tiles regress (R16: MT=32,
//  occ 55%, fused 148us); pass-fusion regresses (R13); scheduling tricks
//  neutral at fixed geometry (R8/R9/R11/R12); coop-launch merge breaks graph
//  capture (R10); bigger tiles blow LDS/AGPR. Not a pipe roofline (all pipes
//  <=25%) — a structural barrier-convoy plateau for this decomposition.
// MFMA 16x16x32 bf16 layouts (HW-verified per guide m89/m91):
//   A[m][k]: m = lane&15, k = (lane>>4)*8 + j   (W row-major: contiguous 16B)
//   B[k][n]: n = lane&15, k = (lane>>4)*8 + j   (Xs row  : contiguous 16B)
//   C/D:     n(atom) = lane&15, m(neuron) = (lane>>4)*4 + reg

#define D 256
#define T 4
#define MT 64            // atoms per block
#define NTHREADS 512     // 8 waves
#define CSTRIDE 32       // cursor padding: one counter per 128B cache line

// swizzled halfword index for element (row=atom, col=feature halfword)
#define XSW(row, col) (((row) << 8) + ((col) ^ (((row) & 7) << 3)))

typedef __attribute__((ext_vector_type(8))) short bf16x8;
typedef __attribute__((ext_vector_type(4))) float f32x4;

__device__ __forceinline__ float bf2f(unsigned short s) {
    union { unsigned u; float f; } c;
    c.u = ((unsigned)s) << 16;
    return c.f;
}
// packed f32x2 -> bf16x2, RNE (MODE default), 1 instr (guide T12 recipe, m240)
__device__ __forceinline__ unsigned cvtpk(float a, float b) {
    unsigned r;
    asm("v_cvt_pk_bf16_f32 %0, %1, %2" : "=v"(r) : "v"(a), "v"(b));
    return r;
}
__device__ __forceinline__ float lo2f(unsigned u) { return bf2f((unsigned short)(u & 0xffffu)); }
__device__ __forceinline__ float hi2f(unsigned u) { return bf2f((unsigned short)(u >> 16)); }
__device__ __forceinline__ float silu(float v) {
    // fast rcp (~1ulp) is fine: result is rounded to bf16 anyway
    return v * __builtin_amdgcn_rcpf(1.f + __expf(-v));
}

// LDS-only barrier (T4): waits own LDS ops (producer side), does NOT drain
// vmcnt -> prefetched global loads stay in flight across the barrier.
__device__ __forceinline__ void barrier_lds() {
    __builtin_amdgcn_sched_barrier(0);
    asm volatile("s_waitcnt lgkmcnt(0)" ::: "memory");
    __builtin_amdgcn_s_barrier();
    __builtin_amdgcn_sched_barrier(0);
}

// ---------------- prep kernel (hist+scatter+convert merged) ----------------
// perm layout: capacity regions, type t's atoms at perm[t*N .. t*N+count[t])
extern "C" __global__ void k_prep(const int* __restrict__ species, int* cursors,
                                  int* __restrict__ perm, int N,
                                  const float* __restrict__ s0, const float* __restrict__ s1,
                                  const float* __restrict__ s2, const float* __restrict__ s3,
                                  unsigned short* __restrict__ d0, unsigned short* __restrict__ d1,
                                  unsigned short* __restrict__ d2, unsigned short* __restrict__ d3, int n4) {
    __shared__ int lh[T], lbase[T];
    int tid = threadIdx.x;
    if (tid < T) lh[tid] = 0;
    __syncthreads();
    int i = blockIdx.x * blockDim.x + tid;
    int t = -1, rank = 0;
    if (i < N) {
        t = species[i];
        rank = atomicAdd(&lh[t], 1);          // LDS atomic: block-local rank
    }
    if (i < n4) {   // weight fp32 -> bf16 (vectorized, cvt_pk); independent path
        float4 v;
        v = ((const float4*)s0)[i]; ((uint2*)d0)[i] = make_uint2(cvtpk(v.x, v.y), cvtpk(v.z, v.w));
        v = ((const float4*)s1)[i]; ((uint2*)d1)[i] = make_uint2(cvtpk(v.x, v.y), cvtpk(v.z, v.w));
        v = ((const float4*)s2)[i]; ((uint2*)d2)[i] = make_uint2(cvtpk(v.x, v.y), cvtpk(v.z, v.w));
        v = ((const float4*)s3)[i]; ((uint2*)d3)[i] = make_uint2(cvtpk(v.x, v.y), cvtpk(v.z, v.w));
    }
    __syncthreads();
    if (tid < T) lbase[tid] = atomicAdd(&cursors[tid * CSTRIDE], lh[tid]);  // 4/block, padded lines
    __syncthreads();
    if (t >= 0) perm[t * N + lbase[t] + rank] = i;
}

// ---------------- fused main kernel ----------------

extern "C" __global__ void __launch_bounds__(NTHREADS, 4)
fused_moe(const float* __restrict__ density,
          const int* __restrict__ perm,
          const int* __restrict__ counts,     // == padded cursors after k_prep
          const unsigned short* __restrict__ W0b,
          const unsigned short* __restrict__ Wab,
          const unsigned short* __restrict__ Wlb,
          const unsigned short* __restrict__ Wfb,
          const float* __restrict__ b0g, const float* __restrict__ bag,
          const float* __restrict__ aag, const float* __restrict__ gg,
          const float* __restrict__ btg, const float* __restrict__ blg,
          const float* __restrict__ bfg, const float* __restrict__ afg,
          const float* __restrict__ Wog, const float* __restrict__ bog,
          float* __restrict__ out, int N)
{
    __shared__ unsigned short Xs[2][MT * D];            // 2 x 32768 B, ping-pong, XOR-swizzled
    __shared__ float Pb0[D], Pba[D], Paa[D], Pg[D], Pbt[D], Pbl[D], Pbf[D], Paf[D], Pwo[D]; // 9216 B
    __shared__ float red1[NTHREADS], red2[NTHREADS];    // 4096 B; also carries mu/rs
    // total LDS = 78848 B -> 2 blocks/CU; VGPR<=128 -> 16 waves/CU

    const int tid = threadIdx.x;

    // ---- XCD-clustered work swizzle (bijective, m204): each XCD gets a
    //      contiguous vb-chunk -> <=2 types -> weights L2-resident ----
    const int nwg = gridDim.x;
    const int qq = nwg >> 3, rr = nwg & 7;
    const int xcd = blockIdx.x & 7, lid = blockIdx.x >> 3;
    const int vb = (xcd < rr ? xcd * (qq + 1) : rr * (qq + 1) + (xcd - rr) * qq) + lid;

    // ---- which (type, tile) am I? ----
    int c[T];
#pragma unroll
    for (int i = 0; i < T; ++i) c[i] = counts[i * CSTRIDE];
    int t = -1, tile = 0, rem = vb;
#pragma unroll
    for (int i = 0; i < T; ++i) {
        int ti = (c[i] + MT - 1) >> 6;
        if (t < 0) {
            if (rem < ti) { t = i; tile = rem; }
            else rem -= ti;
        }
    }
    if (t < 0) return;
    const int bstart = t * N + tile * MT;               // capacity-region base
    const int nrows = min(MT, c[t] - tile * MT);

    const int lane = tid & 63;
    const int w    = tid >> 6;            // wave id 0..7 -> neuron 32-slice
    const int ml   = lane & 15;
    const int qk   = (lane >> 4) * 8;     // A/B fragment k offset
    const int qr   = (lane >> 4) * 4;     // C/D fragment neuron offset

    const size_t wmat = (size_t)t * D * D;
    const unsigned short* W0t = W0b + wmat;
    const unsigned short* Wat = Wab + wmat;
    const unsigned short* Wlt = Wlb + wmat;
    const unsigned short* Wft = Wfb + wmat;

    // ---- A-pipeline state: 2 pair-buffers x (2 ksteps x 2 mi) = 32 VGPR ----
    bf16x8 abuf[2][4];
    // prefill BOTH k-pairs (ksteps 0..3) of W; 8 loads issued before the
    // preceding barrier -> with barrier_lds (no vmcnt drain) they stay in
    // flight across it, hidden under epilogue VALU + barrier wait
    auto prefA = [&](const unsigned short* __restrict__ W) {
#pragma unroll
        for (int p = 0; p < 2; ++p)
#pragma unroll
            for (int s = 0; s < 2; ++s)
#pragma unroll
                for (int mi = 0; mi < 2; ++mi)
                    abuf[p][s * 2 + mi] =
                        *(const bf16x8*)(W + (size_t)(w * 32 + mi * 16 + ml) * D + p * 64 + s * 32 + qk);
    };

    prefA(W0t);                                        // flight hides under gather

    // ---- stage ALL per-type vectors once (tid<256 active) ----
    if (tid < D) {
        int j = t * D + tid;
        Pb0[tid] = b0g[j]; Pba[tid] = bag[j]; Paa[tid] = aag[j];
        Pg[tid]  = gg[j];  Pbt[tid] = btg[j]; Pbl[tid] = blg[j];
        Pbf[tid] = bfg[j]; Paf[tid] = afg[j]; Pwo[tid] = Wog[j];
    }

    // ---- gather X0 (fp32 -> bf16) into Xs[0][atom][feature] (swizzled) ----
#pragma unroll
    for (int p = 0; p < 2; ++p) {
        int row = p * 32 + (tid >> 4);
        int cbase = (tid & 15) * 4;
        if (row < nrows) {
            const float* src = density + (size_t)perm[bstart + row] * D;
#pragma unroll
            for (int j = 0; j < 4; ++j) {
                int col = cbase + j * 64;
                float4 v = *(const float4*)(src + col);
                *(uint2*)(&Xs[0][XSW(row, col)]) = make_uint2(cvtpk(v.x, v.y), cvtpk(v.z, v.w));
            }
        } else {
#pragma unroll
            for (int j = 0; j < 4; ++j)
                *(uint2*)(&Xs[0][XSW(row, cbase + j * 64)]) = make_uint2(0u, 0u);
        }
    }
    barrier_lds();                                      // B1

    f32x4 acc[2][4];                      // 32 AGPRs
    const f32x4 zero4 = {0.f, 0.f, 0.f, 0.f};

    // Software-pipelined GEMM: abuf holds pairs kp (cur) and kp+1; right after
    // the MFMAs consume half-buffer (cur,s), it is refilled with pair kp+2's
    // same-s fragments -> loads stay ~1.5 pairs ahead of use.
    auto do_gemm = [&](const unsigned short* __restrict__ W, const unsigned short* __restrict__ Xb) {
#pragma unroll
        for (int mi = 0; mi < 2; ++mi)
#pragma unroll
            for (int ni = 0; ni < 4; ++ni) acc[mi][ni] = zero4;
#pragma unroll
        for (int kp = 0; kp < 4; ++kp) {               // 4 kstep-pairs
            const int cur = kp & 1;
#pragma unroll
            for (int s = 0; s < 2; ++s) {
                const int k0 = kp * 64 + s * 32;
                bf16x8 b[4];
#pragma unroll
                for (int ni = 0; ni < 4; ++ni)
                    b[ni] = *(const bf16x8*)(Xb + XSW(ni * 16 + ml, k0 + qk));
#pragma unroll
                for (int mi = 0; mi < 2; ++mi)
#pragma unroll
                    for (int ni = 0; ni < 4; ++ni)
                        acc[mi][ni] = __builtin_amdgcn_mfma_f32_16x16x32_bf16(
                            abuf[cur][s * 2 + mi], b[ni], acc[mi][ni], 0, 0, 0);
                if (kp < 2) {   // refill just-consumed half with pair kp+2
                    const int kb = (kp + 2) * 64 + s * 32;
#pragma unroll
                    for (int mi = 0; mi < 2; ++mi)
                        abuf[cur][s * 2 + mi] =
                            *(const bf16x8*)(W + (size_t)(w * 32 + mi * 16 + ml) * D + kb + qk);
                }
            }
        }
    };

    // lane owns atom a0 = ni*16+ml, neurons r0..r0+3 (contiguous)

    // ======== Phase 1: x1 = X0 @ W0^T + b0   (read Xs0, write Xs1) ========
    do_gemm(W0t, Xs[0]);
    prefA(Wat);
#pragma unroll
    for (int mi = 0; mi < 2; ++mi) {
#pragma unroll
        for (int ni = 0; ni < 4; ++ni) {
            int r0 = w * 32 + mi * 16 + qr;
            int a0 = ni * 16 + ml;
            float4 bb = *(const float4*)(Pb0 + r0);
            unsigned p01 = cvtpk(acc[mi][ni][0] + bb.x, acc[mi][ni][1] + bb.y);
            unsigned p23 = cvtpk(acc[mi][ni][2] + bb.z, acc[mi][ni][3] + bb.w);
            *(uint2*)(&Xs[1][XSW(a0, r0)]) = make_uint2(p01, p23);
        }
    }
    barrier_lds();                                      // B2

    // ======== Phase 2: h = alpha_a * silu(x1 @ Wa^T + ba)  (read Xs1, write Xs0) ========
    do_gemm(Wat, Xs[1]);
    prefA(Wlt);
#pragma unroll
    for (int mi = 0; mi < 2; ++mi) {
#pragma unroll
        for (int ni = 0; ni < 4; ++ni) {
            int r0 = w * 32 + mi * 16 + qr;
            int a0 = ni * 16 + ml;
            float4 bb = *(const float4*)(Pba + r0);
            float4 aa = *(const float4*)(Paa + r0);
            float v0 = aa.x * silu(acc[mi][ni][0] + bb.x);
            float v1 = aa.y * silu(acc[mi][ni][1] + bb.y);
            float v2 = aa.z * silu(acc[mi][ni][2] + bb.z);
            float v3 = aa.w * silu(acc[mi][ni][3] + bb.w);
            *(uint2*)(&Xs[0][XSW(a0, r0)]) = make_uint2(cvtpk(v0, v1), cvtpk(v2, v3));
        }
    }
    barrier_lds();                                      // B3

    // ======== LayerNorm per atom: Xs0 IN PLACE (x1 survives in Xs1) ========
    {
        int row = tid & 63, q = tid >> 6;   // thread owns 32 columns of its row
        bf16x8 hv[4];
        float sum = 0.f, ssq = 0.f;
#pragma unroll
        for (int j = 0; j < 4; ++j) {
            hv[j] = *(const bf16x8*)(&Xs[0][XSW(row, q * 32 + j * 8)]);
#pragma unroll
            for (int e = 0; e < 8; ++e) {
                float f = bf2f((unsigned short)hv[j][e]);
                sum += f;
                ssq = fmaf(f, f, ssq);
            }
        }
        red1[tid] = sum; red2[tid] = ssq;
        barrier_lds();                                  // B4
        if (tid < MT) {
            float s = 0.f, sq = 0.f;
#pragma unroll
            for (int k = 0; k < 8; ++k) { s += red1[tid + 64 * k]; sq += red2[tid + 64 * k]; }
            float mu = s * (1.f / D);
            float var = sq * (1.f / D) - mu * mu;
            red1[tid] = mu;
            red2[tid] = rsqrtf(var + 1e-5f);
        }
        barrier_lds();                                  // B5
        float mu = red1[row], rs = red2[row];
#pragma unroll
        for (int j = 0; j < 4; ++j) {
            float n[8];
#pragma unroll
            for (int e = 0; e < 8; ++e) {
                int col = q * 32 + j * 8 + e;
                float f = bf2f((unsigned short)hv[j][e]);
                n[e] = fmaf((f - mu) * rs, Pg[col], Pbt[col]);
            }
            uint4 o = make_uint4(cvtpk(n[0], n[1]), cvtpk(n[2], n[3]),
                                 cvtpk(n[4], n[5]), cvtpk(n[6], n[7]));
            *(uint4*)(&Xs[0][XSW(row, q * 32 + j * 8)]) = o;   // in-place, own cols
        }
    }
    barrier_lds();                                      // B6

    // ======== Phase 3: x3 = x1 + h @ Wl^T + bl  (read Xs0; x1 from Xs1; write Xs1) ========
    do_gemm(Wlt, Xs[0]);
    prefA(Wft);
#pragma unroll
    for (int mi = 0; mi < 2; ++mi) {
#pragma unroll
        for (int ni = 0; ni < 4; ++ni) {
            int r0 = w * 32 + mi * 16 + qr;
            int a0 = ni * 16 + ml;
            float4 bb = *(const float4*)(Pbl + r0);
            uint2 old = *(const uint2*)(&Xs[1][XSW(a0, r0)]);  // x1 (same thread re-writes it)
            float v0 = acc[mi][ni][0] + bb.x + lo2f(old.x);
            float v1 = acc[mi][ni][1] + bb.y + hi2f(old.x);
            float v2 = acc[mi][ni][2] + bb.z + lo2f(old.y);
            float v3 = acc[mi][ni][3] + bb.w + hi2f(old.y);
            *(uint2*)(&Xs[1][XSW(a0, r0)]) = make_uint2(cvtpk(v0, v1), cvtpk(v2, v3));
        }
    }
    barrier_lds();                                      // B7

    // ======== Phase 4: x4 = alpha_f * silu(x3 @ Wf^T + bf)  (read Xs1, write Xs0) ========
    do_gemm(Wft, Xs[1]);
#pragma unroll
    for (int mi = 0; mi < 2; ++mi) {
#pragma unroll
        for (int ni = 0; ni < 4; ++ni) {
            int r0 = w * 32 + mi * 16 + qr;
            int a0 = ni * 16 + ml;
            float4 bb = *(const float4*)(Pbf + r0);
            float4 aa = *(const float4*)(Paf + r0);
            float v0 = aa.x * silu(acc[mi][ni][0] + bb.x);
            float v1 = aa.y * silu(acc[mi][ni][1] + bb.y);
            float v2 = aa.z * silu(acc[mi][ni][2] + bb.z);
            float v3 = aa.w * silu(acc[mi][ni][3] + bb.w);
            *(uint2*)(&Xs[0][XSW(a0, r0)]) = make_uint2(cvtpk(v0, v1), cvtpk(v2, v3));
        }
    }
    barrier_lds();                                      // B8

    // ======== Output: y = x4 . Wo[t] + bo[t]  (read Xs0) ========
    {
        int row = tid & 63, q = tid >> 6;
        float part = 0.f;
#pragma unroll
        for (int j = 0; j < 4; ++j) {
            bf16x8 hv = *(const bf16x8*)(&Xs[0][XSW(row, q * 32 + j * 8)]);
#pragma unroll
            for (int e = 0; e < 8; ++e)
                part = fmaf(bf2f((unsigned short)hv[e]), Pwo[q * 32 + j * 8 + e], part);
        }
        red1[tid] = part;
        barrier_lds();                                  // B9
        if (tid < nrows) {
            float val = bog[t];
#pragma unroll
            for (int k = 0; k < 8; ++k) val += red1[tid + 64 * k];
            out[perm[bstart + tid]] = val;
        }
    }
}

// ---------------- launcher ----------------

extern "C" void kernel_launch(void* const* d_in, const int* in_sizes, int n_in,
                              void* d_out, int out_size, void* d_ws, size_t ws_size,
                              hipStream_t stream) {
    const float* density = (const float*)d_in[0];
    const int*   species = (const int*)d_in[1];
    const float* W0      = (const float*)d_in[2];
    const float* b0      = (const float*)d_in[3];
    const float* Wa      = (const float*)d_in[4];
    const float* ba      = (const float*)d_in[5];
    const float* alpha_a = (const float*)d_in[6];
    const float* gamma   = (const float*)d_in[7];
    const float* beta_ln = (const float*)d_in[8];
    const float* Wl      = (const float*)d_in[9];
    const float* bl      = (const float*)d_in[10];
    const float* Wf      = (const float*)d_in[11];
    const float* bfv     = (const float*)d_in[12];
    const float* alpha_f = (const float*)d_in[13];
    const float* Wo      = (const float*)d_in[14];
    const float* bo      = (const float*)d_in[15];
    float* out = (float*)d_out;
    const int N = in_sizes[1];

    // ws layout: [cursors 4 x 128B = 512B, pad to 1KB] [perm T*N ints = 1MB]
    //            [bf16 weights 4 x 512KB]
    char* ws = (char*)d_ws;
    int* cursors = (int*)ws;
    int* perm    = (int*)(ws + 1024);
    const size_t wsz = (size_t)T * D * D;       // elems per weight tensor
    unsigned short* W0b = (unsigned short*)(ws + 1024 + (size_t)T * N * 4);
    unsigned short* Wab = W0b + wsz;
    unsigned short* Wlb = Wab + wsz;
    unsigned short* Wfb = Wlb + wsz;

    hipMemsetAsync(ws, 0, 512, stream);         // padded cursors
    int n4 = (int)(wsz / 4);
    int pb = ((N > n4 ? N : n4) + 255) / 256;
    k_prep<<<pb, 256, 0, stream>>>(species, cursors, perm, N, W0, Wa, Wl, Wf,
                                   W0b, Wab, Wlb, Wfb, n4);

    int nblocks = (N + MT - 1) / MT + T;
    fused_moe<<<nblocks, NTHREADS, 0, stream>>>(density, perm, cursors, W0b, Wab, Wlb, Wfb,
                                                b0, ba, alpha_a, gamma, beta_ln, bl, bfv, alpha_f,
                                                Wo, bo, out, N);
}

// Round 14
// 193.113 us; speedup vs baseline: 1.2879x; 1.0141x over previous
//
#include <hip/hip_runtime.h>
#include <hip/hip_bf16.h>

// Fused per-type MLP chain (Linear -> ResBlock(silu,LN,Linear) -> silu-Linear -> dot)
// R19 (from R18 @ 195.8us verified; fused ~94-95 at its measured plateau):
//  Last unexplained ledger item: total-minus-fused gap ~100us. Attribution:
//  ~21us = 1024 global cursor atomics (R6 measured ~21ns marginal/atomic),
//  <10us k_prep data work (~7MB warm), ~10us memset+graph barriers, ~60us
//  UNATTRIBUTED. Decisive probe: k_prep rewritten to 1024-thread / 64-block
//  form -> 256 global atomics (4x fewer), 4x fewer block launches; coverage
//  identical (64x1024 = 65536 = N = n4). fused_moe BYTE-IDENTICAL to R18.
//  Predict: total 178-188 if prep-serialization theory right; 193-196 if the
//  gap is fixed harness overhead (then session closes at this state).
// MFMA 16x16x32 bf16 layouts (HW-verified per guide m89/m91):
//   A[m][k]: m = lane&15, k = (lane>>4)*8 + j   (W row-major: contiguous 16B)
//   B[k][n]: n = lane&15, k = (lane>>4)*8 + j   (Xs row  : contiguous 16B)
//   C/D:     n(atom) = lane&15, m(neuron) = (lane>>4)*4 + reg

#define D 256
#define T 4
#define MT 64            // atoms per block
#define NTHREADS 512     // 8 waves (fused kernel)
#define NTPREP 1024      // prep kernel block size (64 blocks for N=65536)
#define CSTRIDE 32       // cursor padding: one counter per 128B cache line

// swizzled halfword index for element (row=atom, col=feature halfword)
#define XSW(row, col) (((row) << 8) + ((col) ^ (((row) & 7) << 3)))

typedef __attribute__((ext_vector_type(8))) short bf16x8;
typedef __attribute__((ext_vector_type(4))) float f32x4;

__device__ __forceinline__ float bf2f(unsigned short s) {
    union { unsigned u; float f; } c;
    c.u = ((unsigned)s) << 16;
    return c.f;
}
// packed f32x2 -> bf16x2, RNE (MODE default), 1 instr (guide T12 recipe, m240)
__device__ __forceinline__ unsigned cvtpk(float a, float b) {
    unsigned r;
    asm("v_cvt_pk_bf16_f32 %0, %1, %2" : "=v"(r) : "v"(a), "v"(b));
    return r;
}
__device__ __forceinline__ float lo2f(unsigned u) { return bf2f((unsigned short)(u & 0xffffu)); }
__device__ __forceinline__ float hi2f(unsigned u) { return bf2f((unsigned short)(u >> 16)); }
__device__ __forceinline__ float silu(float v) {
    // fast rcp (~1ulp) is fine: result is rounded to bf16 anyway
    return v * __builtin_amdgcn_rcpf(1.f + __expf(-v));
}

// LDS-only barrier (T4): waits own LDS ops (producer side), does NOT drain
// vmcnt -> prefetched global loads stay in flight across the barrier.
__device__ __forceinline__ void barrier_lds() {
    __builtin_amdgcn_sched_barrier(0);
    asm volatile("s_waitcnt lgkmcnt(0)" ::: "memory");
    __builtin_amdgcn_s_barrier();
    __builtin_amdgcn_sched_barrier(0);
}

// ---------------- prep kernel (hist+scatter+convert merged) ----------------
// perm layout: capacity regions, type t's atoms at perm[t*N .. t*N+count[t])
// R19: 1024-thread blocks -> 64 blocks -> 256 global atomics (was 1024).
extern "C" __global__ void k_prep(const int* __restrict__ species, int* cursors,
                                  int* __restrict__ perm, int N,
                                  const float* __restrict__ s0, const float* __restrict__ s1,
                                  const float* __restrict__ s2, const float* __restrict__ s3,
                                  unsigned short* __restrict__ d0, unsigned short* __restrict__ d1,
                                  unsigned short* __restrict__ d2, unsigned short* __restrict__ d3, int n4) {
    __shared__ int lh[T], lbase[T];
    int tid = threadIdx.x;
    if (tid < T) lh[tid] = 0;
    __syncthreads();
    int i = blockIdx.x * blockDim.x + tid;
    int t = -1, rank = 0;
    if (i < N) {
        t = species[i];
        rank = atomicAdd(&lh[t], 1);          // LDS atomic: block-local rank
    }
    if (i < n4) {   // weight fp32 -> bf16 (vectorized, cvt_pk); independent path
        float4 v;
        v = ((const float4*)s0)[i]; ((uint2*)d0)[i] = make_uint2(cvtpk(v.x, v.y), cvtpk(v.z, v.w));
        v = ((const float4*)s1)[i]; ((uint2*)d1)[i] = make_uint2(cvtpk(v.x, v.y), cvtpk(v.z, v.w));
        v = ((const float4*)s2)[i]; ((uint2*)d2)[i] = make_uint2(cvtpk(v.x, v.y), cvtpk(v.z, v.w));
        v = ((const float4*)s3)[i]; ((uint2*)d3)[i] = make_uint2(cvtpk(v.x, v.y), cvtpk(v.z, v.w));
    }
    __syncthreads();
    if (tid < T) lbase[tid] = atomicAdd(&cursors[tid * CSTRIDE], lh[tid]);  // 4/block, padded lines
    __syncthreads();
    if (t >= 0) perm[t * N + lbase[t] + rank] = i;
}

// ---------------- fused main kernel (BYTE-IDENTICAL to R18/R15/R12) ----------------

extern "C" __global__ void __launch_bounds__(NTHREADS, 4)
fused_moe(const float* __restrict__ density,
          const int* __restrict__ perm,
          const int* __restrict__ counts,     // == padded cursors after k_prep
          const unsigned short* __restrict__ W0b,
          const unsigned short* __restrict__ Wab,
          const unsigned short* __restrict__ Wlb,
          const unsigned short* __restrict__ Wfb,
          const float* __restrict__ b0g, const float* __restrict__ bag,
          const float* __restrict__ aag, const float* __restrict__ gg,
          const float* __restrict__ btg, const float* __restrict__ blg,
          const float* __restrict__ bfg, const float* __restrict__ afg,
          const float* __restrict__ Wog, const float* __restrict__ bog,
          float* __restrict__ out, int N)
{
    __shared__ unsigned short Xs[2][MT * D];            // 2 x 32768 B, ping-pong, XOR-swizzled
    __shared__ float Pb0[D], Pba[D], Paa[D], Pg[D], Pbt[D], Pbl[D], Pbf[D], Paf[D], Pwo[D]; // 9216 B
    __shared__ float red1[NTHREADS], red2[NTHREADS];    // 4096 B; also carries mu/rs
    // total LDS = 78848 B -> 2 blocks/CU; VGPR<=128 -> 16 waves/CU

    const int tid = threadIdx.x;

    // ---- XCD-clustered work swizzle (bijective, m204): each XCD gets a
    //      contiguous vb-chunk -> <=2 types -> weights L2-resident ----
    const int nwg = gridDim.x;
    const int qq = nwg >> 3, rr = nwg & 7;
    const int xcd = blockIdx.x & 7, lid = blockIdx.x >> 3;
    const int vb = (xcd < rr ? xcd * (qq + 1) : rr * (qq + 1) + (xcd - rr) * qq) + lid;

    // ---- which (type, tile) am I? ----
    int c[T];
#pragma unroll
    for (int i = 0; i < T; ++i) c[i] = counts[i * CSTRIDE];
    int t = -1, tile = 0, rem = vb;
#pragma unroll
    for (int i = 0; i < T; ++i) {
        int ti = (c[i] + MT - 1) >> 6;
        if (t < 0) {
            if (rem < ti) { t = i; tile = rem; }
            else rem -= ti;
        }
    }
    if (t < 0) return;
    const int bstart = t * N + tile * MT;               // capacity-region base
    const int nrows = min(MT, c[t] - tile * MT);

    const int lane = tid & 63;
    const int w    = tid >> 6;            // wave id 0..7 -> neuron 32-slice
    const int ml   = lane & 15;
    const int qk   = (lane >> 4) * 8;     // A/B fragment k offset
    const int qr   = (lane >> 4) * 4;     // C/D fragment neuron offset

    const size_t wmat = (size_t)t * D * D;
    const unsigned short* W0t = W0b + wmat;
    const unsigned short* Wat = Wab + wmat;
    const unsigned short* Wlt = Wlb + wmat;
    const unsigned short* Wft = Wfb + wmat;

    // ---- A-pipeline state: 2 pair-buffers x (2 ksteps x 2 mi) = 32 VGPR ----
    bf16x8 abuf[2][4];
    // prefill BOTH k-pairs (ksteps 0..3) of W; 8 loads issued before the
    // preceding barrier -> with barrier_lds (no vmcnt drain) they stay in
    // flight across it, hidden under epilogue VALU + barrier wait
    auto prefA = [&](const unsigned short* __restrict__ W) {
#pragma unroll
        for (int p = 0; p < 2; ++p)
#pragma unroll
            for (int s = 0; s < 2; ++s)
#pragma unroll
                for (int mi = 0; mi < 2; ++mi)
                    abuf[p][s * 2 + mi] =
                        *(const bf16x8*)(W + (size_t)(w * 32 + mi * 16 + ml) * D + p * 64 + s * 32 + qk);
    };

    prefA(W0t);                                        // flight hides under gather

    // ---- stage ALL per-type vectors once (tid<256 active) ----
    if (tid < D) {
        int j = t * D + tid;
        Pb0[tid] = b0g[j]; Pba[tid] = bag[j]; Paa[tid] = aag[j];
        Pg[tid]  = gg[j];  Pbt[tid] = btg[j]; Pbl[tid] = blg[j];
        Pbf[tid] = bfg[j]; Paf[tid] = afg[j]; Pwo[tid] = Wog[j];
    }

    // ---- gather X0 (fp32 -> bf16) into Xs[0][atom][feature] (swizzled) ----
#pragma unroll
    for (int p = 0; p < 2; ++p) {
        int row = p * 32 + (tid >> 4);
        int cbase = (tid & 15) * 4;
        if (row < nrows) {
            const float* src = density + (size_t)perm[bstart + row] * D;
#pragma unroll
            for (int j = 0; j < 4; ++j) {
                int col = cbase + j * 64;
                float4 v = *(const float4*)(src + col);
                *(uint2*)(&Xs[0][XSW(row, col)]) = make_uint2(cvtpk(v.x, v.y), cvtpk(v.z, v.w));
            }
        } else {
#pragma unroll
            for (int j = 0; j < 4; ++j)
                *(uint2*)(&Xs[0][XSW(row, cbase + j * 64)]) = make_uint2(0u, 0u);
        }
    }
    barrier_lds();                                      // B1

    f32x4 acc[2][4];                      // 32 AGPRs
    const f32x4 zero4 = {0.f, 0.f, 0.f, 0.f};

    // Software-pipelined GEMM: abuf holds pairs kp (cur) and kp+1; right after
    // the MFMAs consume half-buffer (cur,s), it is refilled with pair kp+2's
    // same-s fragments -> loads stay ~1.5 pairs ahead of use.
    auto do_gemm = [&](const unsigned short* __restrict__ W, const unsigned short* __restrict__ Xb) {
#pragma unroll
        for (int mi = 0; mi < 2; ++mi)
#pragma unroll
            for (int ni = 0; ni < 4; ++ni) acc[mi][ni] = zero4;
#pragma unroll
        for (int kp = 0; kp < 4; ++kp) {               // 4 kstep-pairs
            const int cur = kp & 1;
#pragma unroll
            for (int s = 0; s < 2; ++s) {
                const int k0 = kp * 64 + s * 32;
                bf16x8 b[4];
#pragma unroll
                for (int ni = 0; ni < 4; ++ni)
                    b[ni] = *(const bf16x8*)(Xb + XSW(ni * 16 + ml, k0 + qk));
#pragma unroll
                for (int mi = 0; mi < 2; ++mi)
#pragma unroll
                    for (int ni = 0; ni < 4; ++ni)
                        acc[mi][ni] = __builtin_amdgcn_mfma_f32_16x16x32_bf16(
                            abuf[cur][s * 2 + mi], b[ni], acc[mi][ni], 0, 0, 0);
                if (kp < 2) {   // refill just-consumed half with pair kp+2
                    const int kb = (kp + 2) * 64 + s * 32;
#pragma unroll
                    for (int mi = 0; mi < 2; ++mi)
                        abuf[cur][s * 2 + mi] =
                            *(const bf16x8*)(W + (size_t)(w * 32 + mi * 16 + ml) * D + kb + qk);
                }
            }
        }
    };

    // lane owns atom a0 = ni*16+ml, neurons r0..r0+3 (contiguous)

    // ======== Phase 1: x1 = X0 @ W0^T + b0   (read Xs0, write Xs1) ========
    do_gemm(W0t, Xs[0]);
    prefA(Wat);
#pragma unroll
    for (int mi = 0; mi < 2; ++mi) {
#pragma unroll
        for (int ni = 0; ni < 4; ++ni) {
            int r0 = w * 32 + mi * 16 + qr;
            int a0 = ni * 16 + ml;
            float4 bb = *(const float4*)(Pb0 + r0);
            unsigned p01 = cvtpk(acc[mi][ni][0] + bb.x, acc[mi][ni][1] + bb.y);
            unsigned p23 = cvtpk(acc[mi][ni][2] + bb.z, acc[mi][ni][3] + bb.w);
            *(uint2*)(&Xs[1][XSW(a0, r0)]) = make_uint2(p01, p23);
        }
    }
    barrier_lds();                                      // B2

    // ======== Phase 2: h = alpha_a * silu(x1 @ Wa^T + ba)  (read Xs1, write Xs0) ========
    do_gemm(Wat, Xs[1]);
    prefA(Wlt);
#pragma unroll
    for (int mi = 0; mi < 2; ++mi) {
#pragma unroll
        for (int ni = 0; ni < 4; ++ni) {
            int r0 = w * 32 + mi * 16 + qr;
            int a0 = ni * 16 + ml;
            float4 bb = *(const float4*)(Pba + r0);
            float4 aa = *(const float4*)(Paa + r0);
            float v0 = aa.x * silu(acc[mi][ni][0] + bb.x);
            float v1 = aa.y * silu(acc[mi][ni][1] + bb.y);
            float v2 = aa.z * silu(acc[mi][ni][2] + bb.z);
            float v3 = aa.w * silu(acc[mi][ni][3] + bb.w);
            *(uint2*)(&Xs[0][XSW(a0, r0)]) = make_uint2(cvtpk(v0, v1), cvtpk(v2, v3));
        }
    }
    barrier_lds();                                      // B3

    // ======== LayerNorm per atom: Xs0 IN PLACE (x1 survives in Xs1) ========
    {
        int row = tid & 63, q = tid >> 6;   // thread owns 32 columns of its row
        bf16x8 hv[4];
        float sum = 0.f, ssq = 0.f;
#pragma unroll
        for (int j = 0; j < 4; ++j) {
            hv[j] = *(const bf16x8*)(&Xs[0][XSW(row, q * 32 + j * 8)]);
#pragma unroll
            for (int e = 0; e < 8; ++e) {
                float f = bf2f((unsigned short)hv[j][e]);
                sum += f;
                ssq = fmaf(f, f, ssq);
            }
        }
        red1[tid] = sum; red2[tid] = ssq;
        barrier_lds();                                  // B4
        if (tid < MT) {
            float s = 0.f, sq = 0.f;
#pragma unroll
            for (int k = 0; k < 8; ++k) { s += red1[tid + 64 * k]; sq += red2[tid + 64 * k]; }
            float mu = s * (1.f / D);
            float var = sq * (1.f / D) - mu * mu;
            red1[tid] = mu;
            red2[tid] = rsqrtf(var + 1e-5f);
        }
        barrier_lds();                                  // B5
        float mu = red1[row], rs = red2[row];
#pragma unroll
        for (int j = 0; j < 4; ++j) {
            float n[8];
#pragma unroll
            for (int e = 0; e < 8; ++e) {
                int col = q * 32 + j * 8 + e;
                float f = bf2f((unsigned short)hv[j][e]);
                n[e] = fmaf((f - mu) * rs, Pg[col], Pbt[col]);
            }
            uint4 o = make_uint4(cvtpk(n[0], n[1]), cvtpk(n[2], n[3]),
                                 cvtpk(n[4], n[5]), cvtpk(n[6], n[7]));
            *(uint4*)(&Xs[0][XSW(row, q * 32 + j * 8)]) = o;   // in-place, own cols
        }
    }
    barrier_lds();                                      // B6

    // ======== Phase 3: x3 = x1 + h @ Wl^T + bl  (read Xs0; x1 from Xs1; write Xs1) ========
    do_gemm(Wlt, Xs[0]);
    prefA(Wft);
#pragma unroll
    for (int mi = 0; mi < 2; ++mi) {
#pragma unroll
        for (int ni = 0; ni < 4; ++ni) {
            int r0 = w * 32 + mi * 16 + qr;
            int a0 = ni * 16 + ml;
            float4 bb = *(const float4*)(Pbl + r0);
            uint2 old = *(const uint2*)(&Xs[1][XSW(a0, r0)]);  // x1 (same thread re-writes it)
            float v0 = acc[mi][ni][0] + bb.x + lo2f(old.x);
            float v1 = acc[mi][ni][1] + bb.y + hi2f(old.x);
            float v2 = acc[mi][ni][2] + bb.z + lo2f(old.y);
            float v3 = acc[mi][ni][3] + bb.w + hi2f(old.y);
            *(uint2*)(&Xs[1][XSW(a0, r0)]) = make_uint2(cvtpk(v0, v1), cvtpk(v2, v3));
        }
    }
    barrier_lds();                                      // B7

    // ======== Phase 4: x4 = alpha_f * silu(x3 @ Wf^T + bf)  (read Xs1, write Xs0) ========
    do_gemm(Wft, Xs[1]);
#pragma unroll
    for (int mi = 0; mi < 2; ++mi) {
#pragma unroll
        for (int ni = 0; ni < 4; ++ni) {
            int r0 = w * 32 + mi * 16 + qr;
            int a0 = ni * 16 + ml;
            float4 bb = *(const float4*)(Pbf + r0);
            float4 aa = *(const float4*)(Paf + r0);
            float v0 = aa.x * silu(acc[mi][ni][0] + bb.x);
            float v1 = aa.y * silu(acc[mi][ni][1] + bb.y);
            float v2 = aa.z * silu(acc[mi][ni][2] + bb.z);
            float v3 = aa.w * silu(acc[mi][ni][3] + bb.w);
            *(uint2*)(&Xs[0][XSW(a0, r0)]) = make_uint2(cvtpk(v0, v1), cvtpk(v2, v3));
        }
    }
    barrier_lds();                                      // B8

    // ======== Output: y = x4 . Wo[t] + bo[t]  (read Xs0) ========
    {
        int row = tid & 63, q = tid >> 6;
        float part = 0.f;
#pragma unroll
        for (int j = 0; j < 4; ++j) {
            bf16x8 hv = *(const bf16x8*)(&Xs[0][XSW(row, q * 32 + j * 8)]);
#pragma unroll
            for (int e = 0; e < 8; ++e)
                part = fmaf(bf2f((unsigned short)hv[e]), Pwo[q * 32 + j * 8 + e], part);
        }
        red1[tid] = part;
        barrier_lds();                                  // B9
        if (tid < nrows) {
            float val = bog[t];
#pragma unroll
            for (int k = 0; k < 8; ++k) val += red1[tid + 64 * k];
            out[perm[bstart + tid]] = val;
        }
    }
}

// ---------------- launcher ----------------

extern "C" void kernel_launch(void* const* d_in, const int* in_sizes, int n_in,
                              void* d_out, int out_size, void* d_ws, size_t ws_size,
                              hipStream_t stream) {
    const float* density = (const float*)d_in[0];
    const int*   species = (const int*)d_in[1];
    const float* W0      = (const float*)d_in[2];
    const float* b0      = (const float*)d_in[3];
    const float* Wa      = (const float*)d_in[4];
    const float* ba      = (const float*)d_in[5];
    const float* alpha_a = (const float*)d_in[6];
    const float* gamma   = (const float*)d_in[7];
    const float* beta_ln = (const float*)d_in[8];
    const float* Wl      = (const float*)d_in[9];
    const float* bl      = (const float*)d_in[10];
    const float* Wf      = (const float*)d_in[11];
    const float* bfv     = (const float*)d_in[12];
    const float* alpha_f = (const float*)d_in[13];
    const float* Wo      = (const float*)d_in[14];
    const float* bo      = (const float*)d_in[15];
    float* out = (float*)d_out;
    const int N = in_sizes[1];

    // ws layout: [cursors 4 x 128B = 512B, pad to 1KB] [perm T*N ints = 1MB]
    //            [bf16 weights 4 x 512KB]
    char* ws = (char*)d_ws;
    int* cursors = (int*)ws;
    int* perm    = (int*)(ws + 1024);
    const size_t wsz = (size_t)T * D * D;       // elems per weight tensor
    unsigned short* W0b = (unsigned short*)(ws + 1024 + (size_t)T * N * 4);
    unsigned short* Wab = W0b + wsz;
    unsigned short* Wlb = Wab + wsz;
    unsigned short* Wfb = Wlb + wsz;

    hipMemsetAsync(ws, 0, 512, stream);         // padded cursors
    int n4 = (int)(wsz / 4);
    int mx = (N > n4 ? N : n4);
    int pb = (mx + NTPREP - 1) / NTPREP;        // 64 blocks @ N=65536
    k_prep<<<pb, NTPREP, 0, stream>>>(species, cursors, perm, N, W0, Wa, Wl, Wf,
                                      W0b, Wab, Wlb, Wfb, n4);

    int nblocks = (N + MT - 1) / MT + T;
    fused_moe<<<nblocks, NTHREADS, 0, stream>>>(density, perm, cursors, W0b, Wab, Wlb, Wfb,
                                                b0, ba, alpha_a, gamma, beta_ln, bl, bfv, alpha_f,
                                                Wo, bo, out, N);
}